// Round 19
// baseline (358.466 us; speedup 1.0000x reference)
//
#include <hip/hip_runtime.h>
#include <hip/hip_fp16.h>

#define HID 64
#define FSH 7                  // nodes per bucket = 128
#define FB 784                 // buckets: 784*128 = 100352 >= N
#define SCAP 4608              // per-bucket global staging capacity (mean 4082, +8 sigma)
#define FCH 4096               // edges per fillA block (16KB LDS chunk)
// packed record: loc(7b) << 17 | src(17b); requires N <= 131072

__device__ __forceinline__ float2 h2f2(unsigned int bits) {
    __half2 h = __builtin_bit_cast(__half2, bits);
    return __half22float2(h);
}

// ---------------- zero int buffer ----------------
__global__ void zero_kernel(int* __restrict__ p, int n) {
    int i = blockIdx.x * blockDim.x + threadIdx.x;
    if (i < n) p[i] = 0;
}

// ---------------- fill phase A: per-block LDS counting sort + coalesced bucket appends ----------------
__global__ __launch_bounds__(256) void fillA_kernel(const int* __restrict__ src,
                                                    const int* __restrict__ dst,
                                                    int* __restrict__ gcur,
                                                    unsigned int* __restrict__ recA,
                                                    int E) {
    __shared__ unsigned int srec[FCH];          // 16 KB
    __shared__ int hist[FB], lbase[FB], lcur[FB], gpos[FB];   // 12.5 KB
    __shared__ int buf[256];
    int t = threadIdx.x;
    int base = blockIdx.x * FCH;
    int lim = E - base;
    if (lim > FCH) lim = FCH;
    if (lim <= 0) return;
    for (int i = t; i < FB; i += 256) hist[i] = 0;
    __syncthreads();
    for (int i = t; i < lim; i += 256) atomicAdd(&hist[dst[base + i] >> FSH], 1);
    __syncthreads();
    // 4-per-thread scan of hist[0..FB) -> lbase (exclusive)
    int h[4];
#pragma unroll
    for (int j = 0; j < 4; ++j) {
        int idx = 4 * t + j;
        h[j] = (idx < FB) ? hist[idx] : 0;
    }
    int tsum = h[0] + h[1] + h[2] + h[3];
    buf[t] = tsum;
    __syncthreads();
#pragma unroll
    for (int o = 1; o < 256; o <<= 1) {
        int v = (t >= o) ? buf[t - o] : 0;
        __syncthreads();
        buf[t] += v;
        __syncthreads();
    }
    int excl = buf[t] - tsum;
#pragma unroll
    for (int j = 0; j < 4; ++j) {
        int idx = 4 * t + j;
        if (idx < FB) { lbase[idx] = excl; lcur[idx] = excl; }
        excl += h[j];
    }
    __syncthreads();
    // reserve global space (one atomic per bucket per block)
    for (int i = t; i < FB; i += 256) gpos[i] = atomicAdd(&gcur[i], hist[i]);
    __syncthreads();
    // counting-sort records into LDS
    for (int i = t; i < lim; i += 256) {
        int d = dst[base + i];
        int s = src[base + i];
        int bkt = d >> FSH;
        int idx = atomicAdd(&lcur[bkt], 1);
        srec[idx] = ((unsigned int)(d & ((1 << FSH) - 1)) << 17) | (unsigned int)s;
    }
    __syncthreads();
    // coalesced copy of each bucket's run to its global region (8-lane groups, mean run ~5)
    int g8 = t >> 3, lane = t & 7;
    for (int bkt = g8; bkt < FB; bkt += 32) {
        int L = hist[bkt], lb = lbase[bkt], gp = gpos[bkt];
        for (int j = lane; j < L; j += 8) {
            int g = gp + j;
            if (g < SCAP) recA[(size_t)bkt * SCAP + g] = srec[lb + j];
        }
    }
}

// ---------------- fill phase B: inline bucket-prefix + per-bucket LDS CSR + coalesced col ----------------
__global__ __launch_bounds__(256) void fillB_kernel(const int* __restrict__ gcur,
                                                    const unsigned int* __restrict__ recA,
                                                    int* __restrict__ rowptr,
                                                    float* __restrict__ dinv,
                                                    int* __restrict__ col, int N) {
    __shared__ unsigned int lcol[SCAP];         // 18 KB
    __shared__ int hist[128], cur[128], buf[256];
    int b = blockIdx.x, t = threadIdx.x;
    int n0 = b << FSH;
    // rbase = sum_{i<b} min(gcur[i],SCAP)
    int p = 0;
    for (int i = t; i < b; i += 256) p += min(gcur[i], SCAP);
    buf[t] = p;
    __syncthreads();
#pragma unroll
    for (int o = 128; o > 0; o >>= 1) {
        if (t < o) buf[t] += buf[t + o];
        __syncthreads();
    }
    int rbase = buf[0];
    __syncthreads();
    if (t < 128) hist[t] = 0;
    __syncthreads();
    int cnt = gcur[b];
    if (cnt > SCAP) cnt = SCAP;
    const unsigned int* rA = recA + (size_t)b * SCAP;
    for (int r = t; r < cnt; r += 256) atomicAdd(&hist[rA[r] >> 17], 1);
    __syncthreads();
    int a = (t < 128) ? hist[t] : 0;
    buf[t] = a;
    __syncthreads();
#pragma unroll
    for (int o = 1; o < 256; o <<= 1) {
        int v = (t >= o) ? buf[t - o] : 0;
        __syncthreads();
        buf[t] += v;
        __syncthreads();
    }
    int excl = buf[t] - a;           // local exclusive
    if (t < 128) {
        int node = n0 + t;
        if (node <= N) rowptr[node] = rbase + excl;
        if (node < N) dinv[node] = 1.0f / sqrtf((float)(a + 1));
        cur[t] = excl;
    }
    // rowptr[N]: written by the bucket containing node N via guard above (N=100000 < FB*128)
    __syncthreads();
    for (int r = t; r < cnt; r += 256) {
        unsigned int rec = rA[r];
        int pos = atomicAdd(&cur[rec >> 17], 1);  // LDS cursor, local position
        lcol[pos] = rec & 0x1ffffu;
    }
    __syncthreads();
    for (int j = t; j < cnt; j += 256) col[rbase + j] = (int)lcol[j];  // coalesced
}

// ---------------- dense linear (f32 input, K=61) + dinv scale -> f16 rows ----------------
// block = 128 threads, 1 node/thread; x rows staged via LDS (coalesced)
__global__ __launch_bounds__(128) void linscale61_kernel(const float* __restrict__ x,
                                                         const float* __restrict__ W,
                                                         const float* __restrict__ dinv,
                                                         __half* __restrict__ out, int N) {
    __shared__ float4 Wl[61 * 16];     // 15.6 KB
    __shared__ float Xs[128 * 61];     // 31.2 KB
    int t = threadIdx.x;
    const float4* W4 = reinterpret_cast<const float4*>(W);
    for (int i = t; i < 61 * 16; i += 128) Wl[i] = W4[i];
    int nb = blockIdx.x * 128;
    int nrows = N - nb;
    if (nrows > 128) nrows = 128;
    if (nrows <= 0) return;
    const float* srcx = x + (size_t)nb * 61;
    int total = nrows * 61;
    for (int i = t; i < total; i += 128) Xs[i] = srcx[i];
    __syncthreads();
    if (t >= nrows) return;
    int node = nb + t;
    float4 acc[16];
#pragma unroll
    for (int c = 0; c < 16; ++c) acc[c] = make_float4(0.f, 0.f, 0.f, 0.f);
    const float* xr = Xs + t * 61;
    for (int k = 0; k < 61; ++k) {
        float xv = xr[k];
#pragma unroll
        for (int c = 0; c < 16; ++c) {
            float4 w = Wl[k * 16 + c];
            acc[c].x += xv * w.x;
            acc[c].y += xv * w.y;
            acc[c].z += xv * w.z;
            acc[c].w += xv * w.w;
        }
    }
    float dv = dinv[node];
    __half2* o = reinterpret_cast<__half2*>(out + (size_t)node * HID);
#pragma unroll
    for (int c = 0; c < 16; ++c) {
        o[c * 2 + 0] = __floats2half2_rn(acc[c].x * dv, acc[c].y * dv);
        o[c * 2 + 1] = __floats2half2_rn(acc[c].z * dv, acc[c].w * dv);
    }
}

// ---------------- dense linear (f16 input, K=64, uint4-vectorized) + dinv scale -> f16 ----------------
__global__ __launch_bounds__(256) void linscale64h_kernel(const __half* __restrict__ x,
                                                          const float* __restrict__ W,
                                                          const float* __restrict__ dinv,
                                                          __half* __restrict__ out, int N) {
    __shared__ float4 Wl[64 * 16];
    const float4* W4 = reinterpret_cast<const float4*>(W);
    for (int i = threadIdx.x; i < 64 * 16; i += blockDim.x) Wl[i] = W4[i];
    __syncthreads();
    int node = blockIdx.x * blockDim.x + threadIdx.x;
    if (node >= N) return;
    float4 acc[16];
#pragma unroll
    for (int c = 0; c < 16; ++c) acc[c] = make_float4(0.f, 0.f, 0.f, 0.f);
    const uint4* xr4 = reinterpret_cast<const uint4*>(x + ((size_t)node << 6));
#pragma unroll
    for (int c8 = 0; c8 < 8; ++c8) {
        uint4 pk = xr4[c8];
        float2 f0 = h2f2(pk.x), f1 = h2f2(pk.y), f2 = h2f2(pk.z), f3 = h2f2(pk.w);
        float xv[8] = {f0.x, f0.y, f1.x, f1.y, f2.x, f2.y, f3.x, f3.y};
#pragma unroll
        for (int j = 0; j < 8; ++j) {
            int k = c8 * 8 + j;
#pragma unroll
            for (int c = 0; c < 16; ++c) {
                float4 w = Wl[k * 16 + c];
                acc[c].x += xv[j] * w.x;
                acc[c].y += xv[j] * w.y;
                acc[c].z += xv[j] * w.z;
                acc[c].w += xv[j] * w.w;
            }
        }
    }
    float dv = dinv[node];
    __half2* o = reinterpret_cast<__half2*>(out + ((size_t)node << 6));
#pragma unroll
    for (int c = 0; c < 16; ++c) {
        o[c * 2 + 0] = __floats2half2_rn(acc[c].x * dv, acc[c].y * dv);
        o[c * 2 + 1] = __floats2half2_rn(acc[c].z * dv, acc[c].w * dv);
    }
}

// ---------------- gather-aggregate: half2 lanes, 2 rows/wave, 16-deep load pipeline ----------------
// out[d,:] = f16( relu(dinv[d]*(hs[d,:] + sum_e hs[col[e],:]) + b) )
__global__ __launch_bounds__(256) void gather_kernel(const int* __restrict__ rowptr,
                                                     const int* __restrict__ col,
                                                     const float* __restrict__ dinv,
                                                     const __half2* __restrict__ hs2,
                                                     const float* __restrict__ b,
                                                     __half2* __restrict__ out2, int N) {
    int lane = threadIdx.x & 63;
    int hf = lane >> 5;       // which row of the pair
    int gl = lane & 31;       // lane within 32-group = half2 channel pair
    int wid = (blockIdx.x * blockDim.x + threadIdx.x) >> 6;
    int nw = (gridDim.x * blockDim.x) >> 6;
    float bx = b[2 * gl], by = b[2 * gl + 1];
    for (int dbase = wid * 2; dbase < N; dbase += nw * 2) {
        int d = dbase + hf;
        bool act = d < N;
        int dd = act ? d : N - 1;
        int beg = rowptr[dd];
        int end = act ? rowptr[dd + 1] : beg;
        float2 acc0 = __half22float2(hs2[((size_t)dd << 5) + gl]);  // self-loop
        float2 acc1 = make_float2(0.f, 0.f);
        for (int ebase = beg; ebase < end; ebase += 32) {
            int e = ebase + gl;
            int cv = (e < end) ? col[e] : 0;   // OOB lanes -> row 0 (valid, L1-hot)
            int cnt = end - ebase;
            {   // chunk 0: k = 0..15 — 16 loads issued back-to-back
                unsigned int r[16];
#pragma unroll
                for (int k = 0; k < 16; ++k) {
                    int s = __shfl(cv, k, 32);
                    r[k] = *reinterpret_cast<const unsigned int*>(hs2 + ((size_t)s << 5) + gl);
                }
#pragma unroll
                for (int k = 0; k < 16; ++k) {
                    unsigned int bits = (k < cnt) ? r[k] : 0u;
                    float2 v = h2f2(bits);
                    if (k & 1) { acc1.x += v.x; acc1.y += v.y; }
                    else       { acc0.x += v.x; acc0.y += v.y; }
                }
            }
            if (cnt > 16) {   // chunk 1: k = 16..31
                unsigned int r[16];
#pragma unroll
                for (int k = 0; k < 16; ++k) {
                    int s = __shfl(cv, k + 16, 32);
                    r[k] = *reinterpret_cast<const unsigned int*>(hs2 + ((size_t)s << 5) + gl);
                }
#pragma unroll
                for (int k = 0; k < 16; ++k) {
                    unsigned int bits = (k + 16 < cnt) ? r[k] : 0u;
                    float2 v = h2f2(bits);
                    if (k & 1) { acc1.x += v.x; acc1.y += v.y; }
                    else       { acc0.x += v.x; acc0.y += v.y; }
                }
            }
        }
        if (act) {
            float dv = dinv[d];
            float rx = fmaxf(fmaf(acc0.x + acc1.x, dv, bx), 0.f);
            float ry = fmaxf(fmaf(acc0.y + acc1.y, dv, by), 0.f);
            out2[((size_t)d << 5) + gl] = __floats2half2_rn(rx, ry);
        }
    }
}

// ---------------- MLP head, thread-per-node, uint4-vectorized h reads ----------------
__global__ __launch_bounds__(256) void head_kernel(const __half* __restrict__ h,
                                                   const float* __restrict__ Wh1,
                                                   const float* __restrict__ bh1,
                                                   const float* __restrict__ Wh2,
                                                   const float* __restrict__ bh2,
                                                   float* __restrict__ out, int N) {
    __shared__ float4 Wl[64 * 16];
    __shared__ float bhs[64];
    __shared__ float w2s[64];
    const float4* W4 = reinterpret_cast<const float4*>(Wh1);
    for (int i = threadIdx.x; i < 64 * 16; i += blockDim.x) Wl[i] = W4[i];
    if (threadIdx.x < 64) {
        bhs[threadIdx.x] = bh1[threadIdx.x];
        w2s[threadIdx.x] = Wh2[threadIdx.x];
    }
    __syncthreads();
    int node = blockIdx.x * blockDim.x + threadIdx.x;
    if (node >= N) return;
    float4 acc[16];
#pragma unroll
    for (int c = 0; c < 16; ++c) acc[c] = make_float4(0.f, 0.f, 0.f, 0.f);
    const uint4* hr4 = reinterpret_cast<const uint4*>(h + ((size_t)node << 6));
#pragma unroll
    for (int c8 = 0; c8 < 8; ++c8) {
        uint4 pk = hr4[c8];
        float2 f0 = h2f2(pk.x), f1 = h2f2(pk.y), f2 = h2f2(pk.z), f3 = h2f2(pk.w);
        float xv[8] = {f0.x, f0.y, f1.x, f1.y, f2.x, f2.y, f3.x, f3.y};
#pragma unroll
        for (int j = 0; j < 8; ++j) {
            int k = c8 * 8 + j;
#pragma unroll
            for (int c = 0; c < 16; ++c) {
                float4 w = Wl[k * 16 + c];
                acc[c].x += xv[j] * w.x;
                acc[c].y += xv[j] * w.y;
                acc[c].z += xv[j] * w.z;
                acc[c].w += xv[j] * w.w;
            }
        }
    }
    float o = 0.f;
#pragma unroll
    for (int c = 0; c < 16; ++c) {
        o += fmaxf(acc[c].x + bhs[4 * c + 0], 0.f) * w2s[4 * c + 0];
        o += fmaxf(acc[c].y + bhs[4 * c + 1], 0.f) * w2s[4 * c + 1];
        o += fmaxf(acc[c].z + bhs[4 * c + 2], 0.f) * w2s[4 * c + 2];
        o += fmaxf(acc[c].w + bhs[4 * c + 3], 0.f) * w2s[4 * c + 3];
    }
    out[node] = o + bh2[0];
}

extern "C" void kernel_launch(void* const* d_in, const int* in_sizes, int n_in,
                              void* d_out, int out_size, void* d_ws, size_t ws_size,
                              hipStream_t stream) {
    const float* x = (const float*)d_in[0];
    const int* edge = (const int*)d_in[1];   // harness passes integer inputs as int32
    const float* W1 = (const float*)d_in[2];
    const float* b1 = (const float*)d_in[3];
    const float* W2 = (const float*)d_in[4];
    const float* b2 = (const float*)d_in[5];
    const float* W3 = (const float*)d_in[6];
    const float* b3 = (const float*)d_in[7];
    const float* Wh1 = (const float*)d_in[8];
    const float* bh1 = (const float*)d_in[9];
    const float* Wh2 = (const float*)d_in[10];
    const float* bh2 = (const float*)d_in[11];

    int N = in_sizes[0] / 61;   // 100000
    int E = in_sizes[1] / 2;    // 3200000
    const int* srcs = edge;
    const int* dsts = edge + E;
    float* out = (float*)d_out;

    // workspace: dinv(N) | rowptr(N+1) | gcur(FB) | col(E) | Ah(N*64 f16) | Bh(N*64 f16)
    // fill staging recA (FB*SCAP*4 = 14.45MB) aliases Ah+Bh (25.6MB contiguous, dead until linscale1)
    char* ws = (char*)d_ws;
    size_t off = 0;
    auto alloc = [&](size_t bytes) {
        void* p = ws + off;
        off += (bytes + 255) & ~(size_t)255;
        return p;
    };
    float* dinv = (float*)alloc((size_t)N * 4);
    int* rowptr = (int*)alloc((size_t)(N + 1) * 4);
    int* gcur = (int*)alloc((size_t)FB * 4);
    int* col = (int*)alloc((size_t)E * 4);
    __half* Ah = (__half*)alloc((size_t)N * HID * 2);
    __half* Bh = (__half*)alloc((size_t)N * HID * 2);
    if (off > ws_size) return;  // fail cleanly (absmax), not a fault
    unsigned int* recA = (unsigned int*)Ah;  // alias: staging dead after fillB

    int gN = (N + 255) / 256;
    int gA = (E + FCH - 1) / FCH;   // 782
    int gL = (N + 127) / 128;       // 782

    // ---- CSR build (once, reused by all 3 layers) ----
    zero_kernel<<<(FB + 255) / 256, 256, 0, stream>>>(gcur, FB);
    fillA_kernel<<<gA, 256, 0, stream>>>(srcs, dsts, gcur, recA, E);
    fillB_kernel<<<FB, 256, 0, stream>>>(gcur, recA, rowptr, dinv, col, N);

    // ---- layer 1 (K=61) ----
    linscale61_kernel<<<gL, 128, 0, stream>>>(x, W1, dinv, Bh, N);
    gather_kernel<<<4096, 256, 0, stream>>>(rowptr, col, dinv,
                                            (const __half2*)Bh, b1, (__half2*)Ah, N);

    // ---- layer 2 (K=64) ----
    linscale64h_kernel<<<gN, 256, 0, stream>>>(Ah, W2, dinv, Bh, N);
    gather_kernel<<<4096, 256, 0, stream>>>(rowptr, col, dinv,
                                            (const __half2*)Bh, b2, (__half2*)Ah, N);

    // ---- layer 3 (K=64) ----
    linscale64h_kernel<<<gN, 256, 0, stream>>>(Ah, W3, dinv, Bh, N);
    gather_kernel<<<4096, 256, 0, stream>>>(rowptr, col, dinv,
                                            (const __half2*)Bh, b3, (__half2*)Ah, N);

    // ---- MLP head ----
    head_kernel<<<gN, 256, 0, stream>>>(Ah, Wh1, bh1, Wh2, bh2, out, N);
}

// Round 20
// 341.224 us; speedup vs baseline: 1.0505x; 1.0505x over previous
//
#include <hip/hip_runtime.h>
#include <hip/hip_fp16.h>

#define HID 64
#define FSH 8                  // nodes per bucket = 256
#define FB 392                 // buckets: 392*256 = 100352 >= N
#define SCAP 9216              // per-bucket global staging capacity (mean 8163, +11 sigma)
#define FCH 4096               // edges per fillA block (16KB LDS chunk -> high occupancy)
// packed record: loc(8b) << 17 | src(17b); requires N <= 131072

__device__ __forceinline__ float2 h2f2(unsigned int bits) {
    __half2 h = __builtin_bit_cast(__half2, bits);
    return __half22float2(h);
}

// ---------------- zero int buffer ----------------
__global__ void zero_kernel(int* __restrict__ p, int n) {
    int i = blockIdx.x * blockDim.x + threadIdx.x;
    if (i < n) p[i] = 0;
}

// ---------------- fill phase A: per-block LDS counting sort + coalesced bucket appends ----------------
__global__ __launch_bounds__(256) void fillA_kernel(const int* __restrict__ src,
                                                    const int* __restrict__ dst,
                                                    int* __restrict__ gcur,
                                                    unsigned int* __restrict__ recA,
                                                    int E) {
    __shared__ unsigned int srec[FCH];          // 16 KB
    __shared__ int hist[FB], lbase[FB], lcur[FB], gpos[FB];   // 6.3 KB
    __shared__ int buf[256];
    int t = threadIdx.x;
    int base = blockIdx.x * FCH;
    int lim = E - base;
    if (lim > FCH) lim = FCH;
    if (lim <= 0) return;
    for (int i = t; i < FB; i += 256) hist[i] = 0;
    __syncthreads();
    for (int i = t; i < lim; i += 256) atomicAdd(&hist[dst[base + i] >> FSH], 1);
    __syncthreads();
    // pair-scan hist[0..FB) -> lbase (exclusive)
    int i0 = 2 * t, i1 = 2 * t + 1;
    int a0 = (i0 < FB) ? hist[i0] : 0;
    int a1 = (i1 < FB) ? hist[i1] : 0;
    int pair = a0 + a1;
    buf[t] = pair;
    __syncthreads();
#pragma unroll
    for (int o = 1; o < 256; o <<= 1) {
        int v = (t >= o) ? buf[t - o] : 0;
        __syncthreads();
        buf[t] += v;
        __syncthreads();
    }
    int excl = buf[t] - pair;
    if (i0 < FB) { lbase[i0] = excl;      lcur[i0] = excl; }
    if (i1 < FB) { lbase[i1] = excl + a0; lcur[i1] = excl + a0; }
    __syncthreads();
    // reserve global space (one atomic per bucket per block)
    for (int i = t; i < FB; i += 256) gpos[i] = atomicAdd(&gcur[i], hist[i]);
    __syncthreads();
    // counting-sort records into LDS
    for (int i = t; i < lim; i += 256) {
        int d = dst[base + i];
        int s = src[base + i];
        int bkt = d >> FSH;
        int idx = atomicAdd(&lcur[bkt], 1);
        srec[idx] = ((unsigned int)(d & ((1 << FSH) - 1)) << 17) | (unsigned int)s;
    }
    __syncthreads();
    // coalesced copy of each bucket's run to its global region (16-lane groups, mean run ~10)
    int g16 = t >> 4, lane = t & 15;
    for (int bkt = g16; bkt < FB; bkt += 16) {
        int L = hist[bkt], lb = lbase[bkt], gp = gpos[bkt];
        for (int j = lane; j < L; j += 16) {
            int g = gp + j;
            if (g < SCAP) recA[(size_t)bkt * SCAP + g] = srec[lb + j];
        }
    }
}

// ---------------- fill phase B: inline bucket-prefix + per-bucket LDS CSR + coalesced col ----------------
__global__ __launch_bounds__(256) void fillB_kernel(const int* __restrict__ gcur,
                                                    const unsigned int* __restrict__ recA,
                                                    int* __restrict__ rowptr,
                                                    float* __restrict__ dinv,
                                                    int* __restrict__ col, int N) {
    __shared__ unsigned int lcol[SCAP];         // 36 KB
    __shared__ int hist[256], cur[256], buf[256];
    int b = blockIdx.x, t = threadIdx.x;
    int n0 = b << FSH;
    // rbase = sum_{i<b} min(gcur[i],SCAP)
    int p = 0;
    for (int i = t; i < b; i += 256) p += min(gcur[i], SCAP);
    buf[t] = p;
    __syncthreads();
#pragma unroll
    for (int o = 128; o > 0; o >>= 1) {
        if (t < o) buf[t] += buf[t + o];
        __syncthreads();
    }
    int rbase = buf[0];
    __syncthreads();
    hist[t] = 0;
    __syncthreads();
    int cnt = gcur[b];
    if (cnt > SCAP) cnt = SCAP;
    const unsigned int* rA = recA + (size_t)b * SCAP;
    for (int r = t; r < cnt; r += 256) atomicAdd(&hist[rA[r] >> 17], 1);
    __syncthreads();
    int a = hist[t];
    buf[t] = a;
    __syncthreads();
#pragma unroll
    for (int o = 1; o < 256; o <<= 1) {
        int v = (t >= o) ? buf[t - o] : 0;
        __syncthreads();
        buf[t] += v;
        __syncthreads();
    }
    int excl = buf[t] - a;           // local exclusive
    int node = n0 + t;
    if (node <= N) rowptr[node] = rbase + excl;   // includes rowptr[N] at node==N
    if (node < N) dinv[node] = 1.0f / sqrtf((float)(a + 1));
    cur[t] = excl;
    __syncthreads();
    for (int r = t; r < cnt; r += 256) {
        unsigned int rec = rA[r];
        int pos = atomicAdd(&cur[rec >> 17], 1);  // LDS cursor, local position
        lcol[pos] = rec & 0x1ffffu;
    }
    __syncthreads();
    for (int j = t; j < cnt; j += 256) col[rbase + j] = (int)lcol[j];  // coalesced
}

// ---------------- dense linear (f32 input, K=61) + dinv scale -> f16 rows ----------------
__global__ __launch_bounds__(256) void linscale61_kernel(const float* __restrict__ x,
                                                         const float* __restrict__ W,
                                                         const float* __restrict__ dinv,
                                                         __half* __restrict__ out, int N) {
    __shared__ float4 Wl[61 * 16];
    const float4* W4 = reinterpret_cast<const float4*>(W);
    for (int i = threadIdx.x; i < 61 * 16; i += blockDim.x) Wl[i] = W4[i];
    __syncthreads();
    int node = blockIdx.x * blockDim.x + threadIdx.x;
    if (node >= N) return;
    float4 acc[16];
#pragma unroll
    for (int c = 0; c < 16; ++c) acc[c] = make_float4(0.f, 0.f, 0.f, 0.f);
    const float* xr = x + (size_t)node * 61;
    for (int k = 0; k < 61; ++k) {
        float xv = xr[k];
#pragma unroll
        for (int c = 0; c < 16; ++c) {
            float4 w = Wl[k * 16 + c];
            acc[c].x += xv * w.x;
            acc[c].y += xv * w.y;
            acc[c].z += xv * w.z;
            acc[c].w += xv * w.w;
        }
    }
    float dv = dinv[node];
    __half2* o = reinterpret_cast<__half2*>(out + (size_t)node * HID);
#pragma unroll
    for (int c = 0; c < 16; ++c) {
        o[c * 2 + 0] = __floats2half2_rn(acc[c].x * dv, acc[c].y * dv);
        o[c * 2 + 1] = __floats2half2_rn(acc[c].z * dv, acc[c].w * dv);
    }
}

// ---------------- dense linear (f16 input, K=64, uint4-vectorized) + dinv scale -> f16 ----------------
__global__ __launch_bounds__(256) void linscale64h_kernel(const __half* __restrict__ x,
                                                          const float* __restrict__ W,
                                                          const float* __restrict__ dinv,
                                                          __half* __restrict__ out, int N) {
    __shared__ float4 Wl[64 * 16];
    const float4* W4 = reinterpret_cast<const float4*>(W);
    for (int i = threadIdx.x; i < 64 * 16; i += blockDim.x) Wl[i] = W4[i];
    __syncthreads();
    int node = blockIdx.x * blockDim.x + threadIdx.x;
    if (node >= N) return;
    float4 acc[16];
#pragma unroll
    for (int c = 0; c < 16; ++c) acc[c] = make_float4(0.f, 0.f, 0.f, 0.f);
    const uint4* xr4 = reinterpret_cast<const uint4*>(x + ((size_t)node << 6));
#pragma unroll
    for (int c8 = 0; c8 < 8; ++c8) {
        uint4 pk = xr4[c8];
        float2 f0 = h2f2(pk.x), f1 = h2f2(pk.y), f2 = h2f2(pk.z), f3 = h2f2(pk.w);
        float xv[8] = {f0.x, f0.y, f1.x, f1.y, f2.x, f2.y, f3.x, f3.y};
#pragma unroll
        for (int j = 0; j < 8; ++j) {
            int k = c8 * 8 + j;
#pragma unroll
            for (int c = 0; c < 16; ++c) {
                float4 w = Wl[k * 16 + c];
                acc[c].x += xv[j] * w.x;
                acc[c].y += xv[j] * w.y;
                acc[c].z += xv[j] * w.z;
                acc[c].w += xv[j] * w.w;
            }
        }
    }
    float dv = dinv[node];
    __half2* o = reinterpret_cast<__half2*>(out + ((size_t)node << 6));
#pragma unroll
    for (int c = 0; c < 16; ++c) {
        o[c * 2 + 0] = __floats2half2_rn(acc[c].x * dv, acc[c].y * dv);
        o[c * 2 + 1] = __floats2half2_rn(acc[c].z * dv, acc[c].w * dv);
    }
}

// ---------------- gather-aggregate: 16-lane groups, uint2 (4 halves)/lane, 4 rows/wave ----------------
// out[d,:] = f16( relu(dinv[d]*(hs[d,:] + sum_e hs[col[e],:]) + b) )
__global__ __launch_bounds__(256) void gather_kernel(const int* __restrict__ rowptr,
                                                     const int* __restrict__ col,
                                                     const float* __restrict__ dinv,
                                                     const uint2* __restrict__ hs4,
                                                     const float* __restrict__ b,
                                                     uint2* __restrict__ out4, int N) {
    int lane = threadIdx.x & 63;
    int qr = lane >> 4;       // which of the 4 rows
    int gl = lane & 15;       // lane within 16-group = 4-half channel chunk
    int wid = (blockIdx.x * blockDim.x + threadIdx.x) >> 6;
    int nw = (gridDim.x * blockDim.x) >> 6;
    float4 bv = reinterpret_cast<const float4*>(b)[gl];
    for (int dbase = wid * 4; dbase < N; dbase += nw * 4) {
        int d = dbase + qr;
        bool act = d < N;
        int dd = act ? d : N - 1;
        int beg = rowptr[dd];
        int end = act ? rowptr[dd + 1] : beg;
        uint2 sv = hs4[(size_t)dd * 16 + gl];   // self-loop (pre-scaled)
        float2 s0 = h2f2(sv.x), s1 = h2f2(sv.y);
        float4 acc = make_float4(s0.x, s0.y, s1.x, s1.y);
        for (int ebase = beg; ebase < end; ebase += 16) {
            int e = ebase + gl;
            int cv = (e < end) ? col[e] : 0;   // 16 edges per group load
            int cnt = end - ebase;
            if (cnt > 16) cnt = 16;
            uint2 r[16];
#pragma unroll
            for (int k = 0; k < 16; ++k) {
                int s = __shfl(cv, k, 16);
                r[k] = hs4[(size_t)s * 16 + gl];   // 16 independent 8B loads in flight
            }
#pragma unroll
            for (int k = 0; k < 16; ++k) {
                unsigned int bx = (k < cnt) ? r[k].x : 0u;
                unsigned int by = (k < cnt) ? r[k].y : 0u;
                float2 v0 = h2f2(bx), v1 = h2f2(by);
                acc.x += v0.x; acc.y += v0.y; acc.z += v1.x; acc.w += v1.y;
            }
        }
        if (act) {
            float dv = dinv[d];
            float rx = fmaxf(fmaf(acc.x, dv, bv.x), 0.f);
            float ry = fmaxf(fmaf(acc.y, dv, bv.y), 0.f);
            float rz = fmaxf(fmaf(acc.z, dv, bv.z), 0.f);
            float rw = fmaxf(fmaf(acc.w, dv, bv.w), 0.f);
            uint2 o;
            o.x = __builtin_bit_cast(unsigned int, __floats2half2_rn(rx, ry));
            o.y = __builtin_bit_cast(unsigned int, __floats2half2_rn(rz, rw));
            out4[(size_t)d * 16 + gl] = o;
        }
    }
}

// ---------------- MLP head, thread-per-node, uint4-vectorized h reads ----------------
__global__ __launch_bounds__(256) void head_kernel(const __half* __restrict__ h,
                                                   const float* __restrict__ Wh1,
                                                   const float* __restrict__ bh1,
                                                   const float* __restrict__ Wh2,
                                                   const float* __restrict__ bh2,
                                                   float* __restrict__ out, int N) {
    __shared__ float4 Wl[64 * 16];
    __shared__ float bhs[64];
    __shared__ float w2s[64];
    const float4* W4 = reinterpret_cast<const float4*>(Wh1);
    for (int i = threadIdx.x; i < 64 * 16; i += blockDim.x) Wl[i] = W4[i];
    if (threadIdx.x < 64) {
        bhs[threadIdx.x] = bh1[threadIdx.x];
        w2s[threadIdx.x] = Wh2[threadIdx.x];
    }
    __syncthreads();
    int node = blockIdx.x * blockDim.x + threadIdx.x;
    if (node >= N) return;
    float4 acc[16];
#pragma unroll
    for (int c = 0; c < 16; ++c) acc[c] = make_float4(0.f, 0.f, 0.f, 0.f);
    const uint4* hr4 = reinterpret_cast<const uint4*>(h + ((size_t)node << 6));
#pragma unroll
    for (int c8 = 0; c8 < 8; ++c8) {
        uint4 pk = hr4[c8];
        float2 f0 = h2f2(pk.x), f1 = h2f2(pk.y), f2 = h2f2(pk.z), f3 = h2f2(pk.w);
        float xv[8] = {f0.x, f0.y, f1.x, f1.y, f2.x, f2.y, f3.x, f3.y};
#pragma unroll
        for (int j = 0; j < 8; ++j) {
            int k = c8 * 8 + j;
#pragma unroll
            for (int c = 0; c < 16; ++c) {
                float4 w = Wl[k * 16 + c];
                acc[c].x += xv[j] * w.x;
                acc[c].y += xv[j] * w.y;
                acc[c].z += xv[j] * w.z;
                acc[c].w += xv[j] * w.w;
            }
        }
    }
    float o = 0.f;
#pragma unroll
    for (int c = 0; c < 16; ++c) {
        o += fmaxf(acc[c].x + bhs[4 * c + 0], 0.f) * w2s[4 * c + 0];
        o += fmaxf(acc[c].y + bhs[4 * c + 1], 0.f) * w2s[4 * c + 1];
        o += fmaxf(acc[c].z + bhs[4 * c + 2], 0.f) * w2s[4 * c + 2];
        o += fmaxf(acc[c].w + bhs[4 * c + 3], 0.f) * w2s[4 * c + 3];
    }
    out[node] = o + bh2[0];
}

extern "C" void kernel_launch(void* const* d_in, const int* in_sizes, int n_in,
                              void* d_out, int out_size, void* d_ws, size_t ws_size,
                              hipStream_t stream) {
    const float* x = (const float*)d_in[0];
    const int* edge = (const int*)d_in[1];   // harness passes integer inputs as int32
    const float* W1 = (const float*)d_in[2];
    const float* b1 = (const float*)d_in[3];
    const float* W2 = (const float*)d_in[4];
    const float* b2 = (const float*)d_in[5];
    const float* W3 = (const float*)d_in[6];
    const float* b3 = (const float*)d_in[7];
    const float* Wh1 = (const float*)d_in[8];
    const float* bh1 = (const float*)d_in[9];
    const float* Wh2 = (const float*)d_in[10];
    const float* bh2 = (const float*)d_in[11];

    int N = in_sizes[0] / 61;   // 100000
    int E = in_sizes[1] / 2;    // 3200000
    const int* srcs = edge;
    const int* dsts = edge + E;
    float* out = (float*)d_out;

    // workspace: dinv(N) | rowptr(N+1) | gcur(FB) | col(E) | Ah(N*64 f16) | Bh(N*64 f16)
    // fill staging recA (FB*SCAP*4 = 14.45MB) aliases Ah+Bh (25.6MB contiguous, dead until linscale1)
    char* ws = (char*)d_ws;
    size_t off = 0;
    auto alloc = [&](size_t bytes) {
        void* p = ws + off;
        off += (bytes + 255) & ~(size_t)255;
        return p;
    };
    float* dinv = (float*)alloc((size_t)N * 4);
    int* rowptr = (int*)alloc((size_t)(N + 1) * 4);
    int* gcur = (int*)alloc((size_t)FB * 4);
    int* col = (int*)alloc((size_t)E * 4);
    __half* Ah = (__half*)alloc((size_t)N * HID * 2);
    __half* Bh = (__half*)alloc((size_t)N * HID * 2);
    if (off > ws_size) return;  // fail cleanly (absmax), not a fault
    unsigned int* recA = (unsigned int*)Ah;  // alias: staging dead after fillB

    int gN = (N + 255) / 256;
    int gA = (E + FCH - 1) / FCH;   // 782

    // ---- CSR build (once, reused by all 3 layers) ----
    zero_kernel<<<(FB + 255) / 256, 256, 0, stream>>>(gcur, FB);
    fillA_kernel<<<gA, 256, 0, stream>>>(srcs, dsts, gcur, recA, E);
    fillB_kernel<<<FB, 256, 0, stream>>>(gcur, recA, rowptr, dinv, col, N);

    // ---- layer 1 (K=61) ----
    linscale61_kernel<<<gN, 256, 0, stream>>>(x, W1, dinv, Bh, N);
    gather_kernel<<<4096, 256, 0, stream>>>(rowptr, col, dinv,
                                            (const uint2*)Bh, b1, (uint2*)Ah, N);

    // ---- layer 2 (K=64) ----
    linscale64h_kernel<<<gN, 256, 0, stream>>>(Ah, W2, dinv, Bh, N);
    gather_kernel<<<4096, 256, 0, stream>>>(rowptr, col, dinv,
                                            (const uint2*)Bh, b2, (uint2*)Ah, N);

    // ---- layer 3 (K=64) ----
    linscale64h_kernel<<<gN, 256, 0, stream>>>(Ah, W3, dinv, Bh, N);
    gather_kernel<<<4096, 256, 0, stream>>>(rowptr, col, dinv,
                                            (const uint2*)Bh, b3, (uint2*)Ah, N);

    // ---- MLP head ----
    head_kernel<<<gN, 256, 0, stream>>>(Ah, Wh1, bh1, Wh2, bh2, out, N);
}